// Round 1
// baseline (2676.769 us; speedup 1.0000x reference)
//
#include <hip/hip_runtime.h>
#include <math.h>

#define N_NODES 100000
#define N_EDGES 1600000
#define F_INDIM 256
#define HID 64
#define NCLS 40

// ---------------- degree / normalization ----------------

__global__ __launch_bounds__(256) void k_init_deg(float* __restrict__ deg) {
  int i = blockIdx.x * 256 + threadIdx.x;
  if (i < N_NODES) deg[i] = 1.0f;   // self-loop
}

__global__ __launch_bounds__(256) void k_count_deg(const int* __restrict__ col,
                                                   float* __restrict__ deg) {
  int e = blockIdx.x * 256 + threadIdx.x;
  if (e < N_EDGES) atomicAdd(&deg[col[e]], 1.0f);
}

__global__ __launch_bounds__(256) void k_dis(float* __restrict__ deg) {
  int i = blockIdx.x * 256 + threadIdx.x;
  if (i < N_NODES) deg[i] = rsqrtf(deg[i]);   // deg >= 1 always
}

// ---------------- GEMM1: h1 = x @ W1 ; out1 = dis^2 * h1 (self-loop init) ----------------
// 64 rows/block, 256 threads, thread tile 4 rows x 4 cols, k-chunked by 64.
// LDS: xs[64][68] (pad 4 for bank spread + 16B alignment) + ws[64][64] = ~33.8 KB.

__global__ __launch_bounds__(256) void k_gemm1(const float* __restrict__ x,
                                               const float* __restrict__ W1,
                                               const float* __restrict__ dis,
                                               float* __restrict__ h1,
                                               float* __restrict__ out1) {
  __shared__ float xs[64 * 68];
  __shared__ float ws[64 * 64];
  const int tid = threadIdx.x;
  const int tx = tid & 15;        // col group
  const int ty = tid >> 4;        // row group
  const int c0 = tx * 4;
  const int r0 = ty * 4;
  const int rowBase = blockIdx.x * 64;

  float acc[4][4];
#pragma unroll
  for (int j = 0; j < 4; ++j)
#pragma unroll
    for (int i = 0; i < 4; ++i) acc[j][i] = 0.0f;

  for (int kc = 0; kc < F_INDIM; kc += 64) {
    // stage x chunk: 64 rows x 64 k = 1024 float4, 4 per thread
#pragma unroll
    for (int i = 0; i < 4; ++i) {
      int f = tid + 256 * i;
      int r = f >> 4, kq = f & 15;
      int gr = rowBase + r;
      float4 v = make_float4(0.f, 0.f, 0.f, 0.f);
      if (gr < N_NODES) v = *(const float4*)&x[(size_t)gr * F_INDIM + kc + kq * 4];
      *(float4*)&xs[r * 68 + kq * 4] = v;
    }
    // stage W chunk: 64 k x 64 c = 1024 float4
#pragma unroll
    for (int i = 0; i < 4; ++i) {
      int f = tid + 256 * i;
      int k = f >> 4, q = f & 15;
      *(float4*)&ws[k * 64 + q * 4] = *(const float4*)&W1[(size_t)(kc + k) * 64 + q * 4];
    }
    __syncthreads();

    for (int k0 = 0; k0 < 64; k0 += 4) {
      float4 xv[4];
#pragma unroll
      for (int j = 0; j < 4; ++j) xv[j] = *(const float4*)&xs[(r0 + j) * 68 + k0];
#pragma unroll
      for (int kk = 0; kk < 4; ++kk) {
        const float4 wv = *(const float4*)&ws[(k0 + kk) * 64 + c0];
#pragma unroll
        for (int j = 0; j < 4; ++j) {
          const float xk = ((const float*)&xv[j])[kk];
          acc[j][0] += xk * wv.x;
          acc[j][1] += xk * wv.y;
          acc[j][2] += xk * wv.z;
          acc[j][3] += xk * wv.w;
        }
      }
    }
    __syncthreads();
  }

#pragma unroll
  for (int j = 0; j < 4; ++j) {
    int gr = rowBase + r0 + j;
    if (gr < N_NODES) {
      float d = dis[gr];
      float d2 = d * d;
      float4 v = make_float4(acc[j][0], acc[j][1], acc[j][2], acc[j][3]);
      *(float4*)&h1[(size_t)gr * HID + c0] = v;
      float4 s = make_float4(v.x * d2, v.y * d2, v.z * d2, v.w * d2);
      *(float4*)&out1[(size_t)gr * HID + c0] = s;
    }
  }
}

// ---------------- scatter1: out1[col] += dis[r]*dis[c] * h1[row], 64 feats ----------------
// 16 threads per edge, float4 per thread.

__global__ __launch_bounds__(256) void k_scatter1(const int* __restrict__ row,
                                                  const int* __restrict__ col,
                                                  const float* __restrict__ dis,
                                                  const float* __restrict__ h1,
                                                  float* __restrict__ out1) {
  int gid = blockIdx.x * 256 + threadIdx.x;
  int e = gid >> 4;
  int q = gid & 15;
  if (e >= N_EDGES) return;
  int r = row[e];
  int c = col[e];
  float nrm = dis[r] * dis[c];
  float4 v = *(const float4*)&h1[(size_t)r * HID + q * 4];
  float* o = &out1[(size_t)c * HID + q * 4];
  atomicAdd(o + 0, nrm * v.x);
  atomicAdd(o + 1, nrm * v.y);
  atomicAdd(o + 2, nrm * v.z);
  atomicAdd(o + 3, nrm * v.w);
}

// ---------------- GEMM2: g = relu(out1 + b1) @ W2 ; out2 = dis^2 * g ----------------
// 128 rows/block, 256 threads, thread tile 4 rows x 5 cols.
// LDS: xs[128][68] + ws2[64*40] = ~44 KB. relu+bias folded into staging.

__global__ __launch_bounds__(256) void k_gemm2(const float* __restrict__ out1,
                                               const float* __restrict__ W2,
                                               const float* __restrict__ b1,
                                               const float* __restrict__ dis,
                                               float* __restrict__ g,
                                               float* __restrict__ out2) {
  __shared__ float xs[128 * 68];
  __shared__ float ws2[64 * NCLS];
  const int tid = threadIdx.x;
  const int cg = tid & 7;        // col group: 8 groups x 5 cols = 40
  const int rg = tid >> 3;       // row group: 32 groups x 4 rows = 128
  const int c0 = cg * 5;
  const int r0 = rg * 4;
  const int rowBase = blockIdx.x * 128;

  // stage W2 (64x40 = 640 float4)
#pragma unroll
  for (int i = 0; i < 3; ++i) {
    int f = tid + 256 * i;
    if (f < 640) *(float4*)&ws2[f * 4] = *(const float4*)&W2[f * 4];
  }
  // stage x: 128 rows x 64 k, relu(v + b1) applied
#pragma unroll
  for (int i = 0; i < 8; ++i) {
    int f = tid + 256 * i;
    int r = f >> 4, kq = f & 15;
    int gr = rowBase + r;
    float4 v = make_float4(0.f, 0.f, 0.f, 0.f);
    if (gr < N_NODES) {
      v = *(const float4*)&out1[(size_t)gr * HID + kq * 4];
      float4 bv = *(const float4*)&b1[kq * 4];
      v.x = fmaxf(v.x + bv.x, 0.f);
      v.y = fmaxf(v.y + bv.y, 0.f);
      v.z = fmaxf(v.z + bv.z, 0.f);
      v.w = fmaxf(v.w + bv.w, 0.f);
    }
    *(float4*)&xs[r * 68 + kq * 4] = v;
  }
  __syncthreads();

  float acc[4][5];
#pragma unroll
  for (int j = 0; j < 4; ++j)
#pragma unroll
    for (int i = 0; i < 5; ++i) acc[j][i] = 0.0f;

  for (int k0 = 0; k0 < HID; k0 += 4) {
    float4 xv[4];
#pragma unroll
    for (int j = 0; j < 4; ++j) xv[j] = *(const float4*)&xs[(r0 + j) * 68 + k0];
#pragma unroll
    for (int kk = 0; kk < 4; ++kk) {
      const float* wrow = &ws2[(k0 + kk) * NCLS + c0];
      float w0 = wrow[0], w1 = wrow[1], w2 = wrow[2], w3 = wrow[3], w4 = wrow[4];
#pragma unroll
      for (int j = 0; j < 4; ++j) {
        const float xk = ((const float*)&xv[j])[kk];
        acc[j][0] += xk * w0;
        acc[j][1] += xk * w1;
        acc[j][2] += xk * w2;
        acc[j][3] += xk * w3;
        acc[j][4] += xk * w4;
      }
    }
  }

#pragma unroll
  for (int j = 0; j < 4; ++j) {
    int gr = rowBase + r0 + j;
    if (gr < N_NODES) {
      float d = dis[gr];
      float d2 = d * d;
#pragma unroll
      for (int i = 0; i < 5; ++i) {
        float val = acc[j][i];
        g[(size_t)gr * NCLS + c0 + i] = val;
        out2[(size_t)gr * NCLS + c0 + i] = d2 * val;
      }
    }
  }
}

// ---------------- scatter2: out2[col] += dis[r]*dis[c] * g[row], 40 feats ----------------
// 10 threads per edge, float4 per thread.

__global__ __launch_bounds__(256) void k_scatter2(const int* __restrict__ row,
                                                  const int* __restrict__ col,
                                                  const float* __restrict__ dis,
                                                  const float* __restrict__ g,
                                                  float* __restrict__ out2) {
  int gid = blockIdx.x * 256 + threadIdx.x;
  int e = gid / 10;
  int q = gid - e * 10;
  if (e >= N_EDGES) return;
  int r = row[e];
  int c = col[e];
  float nrm = dis[r] * dis[c];
  float4 v = *(const float4*)&g[(size_t)r * NCLS + q * 4];
  float* o = &out2[(size_t)c * NCLS + q * 4];
  atomicAdd(o + 0, nrm * v.x);
  atomicAdd(o + 1, nrm * v.y);
  atomicAdd(o + 2, nrm * v.z);
  atomicAdd(o + 3, nrm * v.w);
}

// ---------------- log_softmax (adds b2), one wave per row ----------------

__global__ __launch_bounds__(256) void k_logsoftmax(float* __restrict__ out,
                                                    const float* __restrict__ b2) {
  int gid = blockIdx.x * 256 + threadIdx.x;
  int wid = gid >> 6;
  int lane = threadIdx.x & 63;
  if (wid >= N_NODES) return;
  float val = 0.0f;
  float v = -INFINITY;
  if (lane < NCLS) {
    val = out[(size_t)wid * NCLS + lane] + b2[lane];
    v = val;
  }
#pragma unroll
  for (int off = 32; off > 0; off >>= 1) v = fmaxf(v, __shfl_xor(v, off));
  float ex = (lane < NCLS) ? expf(val - v) : 0.0f;
  float s = ex;
#pragma unroll
  for (int off = 32; off > 0; off >>= 1) s += __shfl_xor(s, off);
  float ls = logf(s);
  if (lane < NCLS) out[(size_t)wid * NCLS + lane] = val - v - ls;
}

// ---------------- launch ----------------

extern "C" void kernel_launch(void* const* d_in, const int* in_sizes, int n_in,
                              void* d_out, int out_size, void* d_ws, size_t ws_size,
                              hipStream_t stream) {
  const float* x  = (const float*)d_in[0];
  const int*   ei = (const int*)d_in[1];
  const float* W1 = (const float*)d_in[2];
  const float* b1 = (const float*)d_in[3];
  const float* W2 = (const float*)d_in[4];
  const float* b2 = (const float*)d_in[5];
  float* out = (float*)d_out;

  const int* row = ei;             // edge_index[0]
  const int* col = ei + N_EDGES;   // edge_index[1]

  float* bufA = (float*)d_ws;                       // h1 then g   (N*64 floats)
  float* bufB = bufA + (size_t)N_NODES * HID;       // out1 agg    (N*64 floats)
  float* deg  = bufB + (size_t)N_NODES * HID;       // deg -> dis  (N floats)

  k_init_deg<<<(N_NODES + 255) / 256, 256, 0, stream>>>(deg);
  k_count_deg<<<(N_EDGES + 255) / 256, 256, 0, stream>>>(col, deg);
  k_dis<<<(N_NODES + 255) / 256, 256, 0, stream>>>(deg);

  k_gemm1<<<(N_NODES + 63) / 64, 256, 0, stream>>>(x, W1, deg, bufA, bufB);
  k_scatter1<<<(N_EDGES * 16 + 255) / 256, 256, 0, stream>>>(row, col, deg, bufA, bufB);

  k_gemm2<<<(N_NODES + 127) / 128, 256, 0, stream>>>(bufB, W2, b1, deg, bufA, out);
  k_scatter2<<<((long)N_EDGES * 10 + 255) / 256, 256, 0, stream>>>(row, col, deg, bufA, out);

  k_logsoftmax<<<(N_NODES * 64 + 255) / 256, 256, 0, stream>>>(out, b2);
}

// Round 2
// 645.405 us; speedup vs baseline: 4.1474x; 4.1474x over previous
//
#include <hip/hip_runtime.h>
#include <math.h>

#define N_NODES 100000
#define N_EDGES 1600000
#define F_INDIM 256
#define HID 64
#define NCLS 40
#define NB_SCAN 391   // ceil(N_NODES/256)

// ---------------- degree / norm / CSR build ----------------

__global__ __launch_bounds__(256) void k_zero_deg(int* __restrict__ degi) {
  int i = blockIdx.x * 256 + threadIdx.x;
  if (i < N_NODES) degi[i] = 0;
}

__global__ __launch_bounds__(256) void k_count(const int* __restrict__ col,
                                               int* __restrict__ degi) {
  int e = blockIdx.x * 256 + threadIdx.x;
  if (e < N_EDGES) atomicAdd(&degi[col[e]], 1);
}

__global__ __launch_bounds__(256) void k_dis(const int* __restrict__ degi,
                                             float* __restrict__ dis,
                                             int* __restrict__ start) {
  int i = blockIdx.x * 256 + threadIdx.x;
  if (i < N_NODES) dis[i] = rsqrtf((float)(degi[i] + 1));  // +1 self-loop
  if (i == 0) start[N_NODES] = N_EDGES;   // scan total is known
}

// per-block exclusive scan of degi -> start (partial), block totals -> bsum
__global__ __launch_bounds__(256) void k_scan1(const int* __restrict__ degi,
                                               int* __restrict__ start,
                                               int* __restrict__ bsum) {
  __shared__ int s[256];
  const int t = threadIdx.x;
  const int i = blockIdx.x * 256 + t;
  int v = (i < N_NODES) ? degi[i] : 0;
  s[t] = v;
  __syncthreads();
#pragma unroll
  for (int off = 1; off < 256; off <<= 1) {
    int u = (t >= off) ? s[t - off] : 0;
    __syncthreads();
    s[t] += u;
    __syncthreads();
  }
  if (i < N_NODES) start[i] = s[t] - v;          // exclusive within block
  if (t == 255) bsum[blockIdx.x] = s[255];
}

// single-block scan of the NB_SCAN block totals
__global__ __launch_bounds__(512) void k_scan2(const int* __restrict__ bsum,
                                               int* __restrict__ bsumS) {
  __shared__ int s[512];
  const int t = threadIdx.x;
  int v = (t < NB_SCAN) ? bsum[t] : 0;
  s[t] = v;
  __syncthreads();
#pragma unroll
  for (int off = 1; off < 512; off <<= 1) {
    int u = (t >= off) ? s[t - off] : 0;
    __syncthreads();
    s[t] += u;
    __syncthreads();
  }
  if (t < NB_SCAN) bsumS[t] = s[t] - v;
}

__global__ __launch_bounds__(256) void k_scan3(int* __restrict__ start,
                                               int* __restrict__ cursor,
                                               const int* __restrict__ bsumS) {
  int i = blockIdx.x * 256 + threadIdx.x;
  if (i < N_NODES) {
    int val = start[i] + bsumS[blockIdx.x];
    start[i] = val;
    cursor[i] = val;
  }
}

// bucket edges by destination: edata[pos] = {src, norm}
__global__ __launch_bounds__(256) void k_build(const int* __restrict__ row,
                                               const int* __restrict__ col,
                                               const float* __restrict__ dis,
                                               int* __restrict__ cursor,
                                               int2* __restrict__ edata) {
  int e = blockIdx.x * 256 + threadIdx.x;
  if (e >= N_EDGES) return;
  int r = row[e];
  int c = col[e];
  int pos = atomicAdd(&cursor[c], 1);
  edata[pos] = make_int2(r, __float_as_int(dis[r] * dis[c]));
}

// ---------------- GEMM1: h1 = x @ W1 ----------------
// 64 rows/block, 256 threads, thread tile 4x4, k-chunked by 64.

__global__ __launch_bounds__(256) void k_gemm1(const float* __restrict__ x,
                                               const float* __restrict__ W1,
                                               float* __restrict__ h1) {
  __shared__ float xs[64 * 68];
  __shared__ float ws[64 * 64];
  const int tid = threadIdx.x;
  const int c0 = (tid & 15) * 4;
  const int r0 = (tid >> 4) * 4;
  const int rowBase = blockIdx.x * 64;

  float acc[4][4];
#pragma unroll
  for (int j = 0; j < 4; ++j)
#pragma unroll
    for (int i = 0; i < 4; ++i) acc[j][i] = 0.0f;

  for (int kc = 0; kc < F_INDIM; kc += 64) {
#pragma unroll
    for (int i = 0; i < 4; ++i) {
      int f = tid + 256 * i;
      int r = f >> 4, kq = f & 15;
      int gr = rowBase + r;
      float4 v = make_float4(0.f, 0.f, 0.f, 0.f);
      if (gr < N_NODES) v = *(const float4*)&x[(size_t)gr * F_INDIM + kc + kq * 4];
      *(float4*)&xs[r * 68 + kq * 4] = v;
    }
#pragma unroll
    for (int i = 0; i < 4; ++i) {
      int f = tid + 256 * i;
      int k = f >> 4, q = f & 15;
      *(float4*)&ws[k * 64 + q * 4] = *(const float4*)&W1[(size_t)(kc + k) * 64 + q * 4];
    }
    __syncthreads();

    for (int k0 = 0; k0 < 64; k0 += 4) {
      float4 xv[4];
#pragma unroll
      for (int j = 0; j < 4; ++j) xv[j] = *(const float4*)&xs[(r0 + j) * 68 + k0];
#pragma unroll
      for (int kk = 0; kk < 4; ++kk) {
        const float4 wv = *(const float4*)&ws[(k0 + kk) * 64 + c0];
#pragma unroll
        for (int j = 0; j < 4; ++j) {
          const float xk = ((const float*)&xv[j])[kk];
          acc[j][0] += xk * wv.x;
          acc[j][1] += xk * wv.y;
          acc[j][2] += xk * wv.z;
          acc[j][3] += xk * wv.w;
        }
      }
    }
    __syncthreads();
  }

#pragma unroll
  for (int j = 0; j < 4; ++j) {
    int gr = rowBase + r0 + j;
    if (gr < N_NODES)
      *(float4*)&h1[(size_t)gr * HID + c0] =
          make_float4(acc[j][0], acc[j][1], acc[j][2], acc[j][3]);
  }
}

// ---------------- agg1: out1[n] = dis[n]^2*h1[n] + sum_e norm*h1[src] ----------------
// one 64-lane wave per node, lane = feature.

__global__ __launch_bounds__(256) void k_agg1(const int2* __restrict__ edata,
                                              const int* __restrict__ start,
                                              const float* __restrict__ dis,
                                              const float* __restrict__ h1,
                                              float* __restrict__ out1) {
  int gid = blockIdx.x * 256 + threadIdx.x;
  int wid = gid >> 6;
  int lane = gid & 63;
  if (wid >= N_NODES) return;
  int s0 = start[wid];
  int e0 = start[wid + 1];
  float d = dis[wid];
  float acc = d * d * h1[(size_t)wid * HID + lane];
  for (int i = s0; i < e0; ++i) {
    int2 ed = edata[i];
    acc += __int_as_float(ed.y) * h1[(size_t)ed.x * HID + lane];
  }
  out1[(size_t)wid * HID + lane] = acc;
}

// ---------------- GEMM2: g = relu(out1 + b1) @ W2 ----------------

__global__ __launch_bounds__(256) void k_gemm2(const float* __restrict__ out1,
                                               const float* __restrict__ W2,
                                               const float* __restrict__ b1,
                                               float* __restrict__ g) {
  __shared__ float xs[128 * 68];
  __shared__ float ws2[64 * NCLS];
  const int tid = threadIdx.x;
  const int c0 = (tid & 7) * 5;
  const int r0 = (tid >> 3) * 4;
  const int rowBase = blockIdx.x * 128;

#pragma unroll
  for (int i = 0; i < 3; ++i) {
    int f = tid + 256 * i;
    if (f < 640) *(float4*)&ws2[f * 4] = *(const float4*)&W2[f * 4];
  }
#pragma unroll
  for (int i = 0; i < 8; ++i) {
    int f = tid + 256 * i;
    int r = f >> 4, kq = f & 15;
    int gr = rowBase + r;
    float4 v = make_float4(0.f, 0.f, 0.f, 0.f);
    if (gr < N_NODES) {
      v = *(const float4*)&out1[(size_t)gr * HID + kq * 4];
      float4 bv = *(const float4*)&b1[kq * 4];
      v.x = fmaxf(v.x + bv.x, 0.f);
      v.y = fmaxf(v.y + bv.y, 0.f);
      v.z = fmaxf(v.z + bv.z, 0.f);
      v.w = fmaxf(v.w + bv.w, 0.f);
    }
    *(float4*)&xs[r * 68 + kq * 4] = v;
  }
  __syncthreads();

  float acc[4][5];
#pragma unroll
  for (int j = 0; j < 4; ++j)
#pragma unroll
    for (int i = 0; i < 5; ++i) acc[j][i] = 0.0f;

  for (int k0 = 0; k0 < HID; k0 += 4) {
    float4 xv[4];
#pragma unroll
    for (int j = 0; j < 4; ++j) xv[j] = *(const float4*)&xs[(r0 + j) * 68 + k0];
#pragma unroll
    for (int kk = 0; kk < 4; ++kk) {
      const float* wrow = &ws2[(k0 + kk) * NCLS + c0];
      float w0 = wrow[0], w1 = wrow[1], w2 = wrow[2], w3 = wrow[3], w4 = wrow[4];
#pragma unroll
      for (int j = 0; j < 4; ++j) {
        const float xk = ((const float*)&xv[j])[kk];
        acc[j][0] += xk * w0;
        acc[j][1] += xk * w1;
        acc[j][2] += xk * w2;
        acc[j][3] += xk * w3;
        acc[j][4] += xk * w4;
      }
    }
  }

#pragma unroll
  for (int j = 0; j < 4; ++j) {
    int gr = rowBase + r0 + j;
    if (gr < N_NODES) {
#pragma unroll
      for (int i = 0; i < 5; ++i)
        g[(size_t)gr * NCLS + c0 + i] = acc[j][i];
    }
  }
}

// ---------------- agg2: out[n] = dis[n]^2*g[n] + sum_e norm*g[src] ----------------
// packed: thread = (node, feat) with 40 feats/node.

__global__ __launch_bounds__(256) void k_agg2(const int2* __restrict__ edata,
                                              const int* __restrict__ start,
                                              const float* __restrict__ dis,
                                              const float* __restrict__ g,
                                              float* __restrict__ out) {
  int gid = blockIdx.x * 256 + threadIdx.x;
  if (gid >= N_NODES * NCLS) return;
  int node = gid / NCLS;
  int f = gid - node * NCLS;
  int s0 = start[node];
  int e0 = start[node + 1];
  float d = dis[node];
  float acc = d * d * g[(size_t)node * NCLS + f];
  for (int i = s0; i < e0; ++i) {
    int2 ed = edata[i];
    acc += __int_as_float(ed.y) * g[(size_t)ed.x * NCLS + f];
  }
  out[(size_t)node * NCLS + f] = acc;
}

// ---------------- log_softmax (adds b2), one wave per row ----------------

__global__ __launch_bounds__(256) void k_logsoftmax(float* __restrict__ out,
                                                    const float* __restrict__ b2) {
  int gid = blockIdx.x * 256 + threadIdx.x;
  int wid = gid >> 6;
  int lane = threadIdx.x & 63;
  if (wid >= N_NODES) return;
  float val = 0.0f;
  float v = -INFINITY;
  if (lane < NCLS) {
    val = out[(size_t)wid * NCLS + lane] + b2[lane];
    v = val;
  }
#pragma unroll
  for (int off = 32; off > 0; off >>= 1) v = fmaxf(v, __shfl_xor(v, off));
  float ex = (lane < NCLS) ? expf(val - v) : 0.0f;
  float s = ex;
#pragma unroll
  for (int off = 32; off > 0; off >>= 1) s += __shfl_xor(s, off);
  float ls = logf(s);
  if (lane < NCLS) out[(size_t)wid * NCLS + lane] = val - v - ls;
}

// ---------------- launch ----------------

extern "C" void kernel_launch(void* const* d_in, const int* in_sizes, int n_in,
                              void* d_out, int out_size, void* d_ws, size_t ws_size,
                              hipStream_t stream) {
  const float* x  = (const float*)d_in[0];
  const int*   ei = (const int*)d_in[1];
  const float* W1 = (const float*)d_in[2];
  const float* b1 = (const float*)d_in[3];
  const float* W2 = (const float*)d_in[4];
  const float* b2 = (const float*)d_in[5];
  float* out = (float*)d_out;

  const int* row = ei;             // edge_index[0] = src
  const int* col = ei + N_EDGES;   // edge_index[1] = dst

  // workspace layout (~65.6 MB)
  int2*  edata  = (int2*)d_ws;                          // E
  float* h1     = (float*)(edata + N_EDGES);            // N*64  (g aliases h1 later)
  float* out1   = h1 + (size_t)N_NODES * HID;           // N*64
  float* dis    = out1 + (size_t)N_NODES * HID;         // N
  int*   degi   = (int*)(dis + N_NODES);                // N
  int*   start  = degi + N_NODES;                       // N+1
  int*   cursor = start + N_NODES + 1;                  // N
  int*   bsum   = cursor + N_NODES;                     // NB_SCAN
  int*   bsumS  = bsum + NB_SCAN;                       // NB_SCAN
  float* g      = h1;                                   // N*40, reuse

  const int gridN = (N_NODES + 255) / 256;     // 391
  const int gridE = (N_EDGES + 255) / 256;

  k_zero_deg<<<gridN, 256, 0, stream>>>(degi);
  k_count<<<gridE, 256, 0, stream>>>(col, degi);
  k_dis<<<gridN, 256, 0, stream>>>(degi, dis, start);
  k_scan1<<<gridN, 256, 0, stream>>>(degi, start, bsum);
  k_scan2<<<1, 512, 0, stream>>>(bsum, bsumS);
  k_scan3<<<gridN, 256, 0, stream>>>(start, cursor, bsumS);
  k_build<<<gridE, 256, 0, stream>>>(row, col, dis, cursor, edata);

  k_gemm1<<<(N_NODES + 63) / 64, 256, 0, stream>>>(x, W1, h1);
  k_agg1<<<(N_NODES * 64 + 255) / 256, 256, 0, stream>>>(edata, start, dis, h1, out1);

  k_gemm2<<<(N_NODES + 127) / 128, 256, 0, stream>>>(out1, W2, b1, g);
  k_agg2<<<(N_NODES * NCLS + 255) / 256, 256, 0, stream>>>(edata, start, dis, g, out);

  k_logsoftmax<<<(N_NODES * 64 + 255) / 256, 256, 0, stream>>>(out, b2);
}

// Round 3
// 508.893 us; speedup vs baseline: 5.2600x; 1.2683x over previous
//
#include <hip/hip_runtime.h>
#include <math.h>

#define N_NODES 100000
#define N_EDGES 1600000
#define F_INDIM 256
#define HID 64
#define NCLS 40
#define NB_SCAN 391   // ceil(N_NODES/256)

// ---- bf16 helpers (RNE) ----
__device__ __forceinline__ unsigned short f2bf(float f) {
  unsigned u = __float_as_uint(f);
  unsigned r = (u + 0x7FFFu + ((u >> 16) & 1u)) >> 16;
  return (unsigned short)r;
}
__device__ __forceinline__ float bf2f(unsigned short h) {
  return __uint_as_float(((unsigned)h) << 16);
}

// ---------------- degree / norm / CSR build ----------------

__global__ __launch_bounds__(256) void k_zero_deg(int* __restrict__ degi) {
  int i = blockIdx.x * 256 + threadIdx.x;
  if (i < N_NODES) degi[i] = 0;
}

__global__ __launch_bounds__(256) void k_count(const int* __restrict__ col,
                                               int* __restrict__ degi) {
  int e = blockIdx.x * 256 + threadIdx.x;
  if (e < N_EDGES) atomicAdd(&degi[col[e]], 1);
}

__global__ __launch_bounds__(256) void k_dis(const int* __restrict__ degi,
                                             float* __restrict__ dis,
                                             int* __restrict__ start) {
  int i = blockIdx.x * 256 + threadIdx.x;
  if (i < N_NODES) dis[i] = rsqrtf((float)(degi[i] + 1));  // +1 self-loop
  if (i == 0) start[N_NODES] = N_EDGES;
}

__global__ __launch_bounds__(256) void k_scan1(const int* __restrict__ degi,
                                               int* __restrict__ start,
                                               int* __restrict__ bsum) {
  __shared__ int s[256];
  const int t = threadIdx.x;
  const int i = blockIdx.x * 256 + t;
  int v = (i < N_NODES) ? degi[i] : 0;
  s[t] = v;
  __syncthreads();
#pragma unroll
  for (int off = 1; off < 256; off <<= 1) {
    int u = (t >= off) ? s[t - off] : 0;
    __syncthreads();
    s[t] += u;
    __syncthreads();
  }
  if (i < N_NODES) start[i] = s[t] - v;
  if (t == 255) bsum[blockIdx.x] = s[255];
}

__global__ __launch_bounds__(512) void k_scan2(const int* __restrict__ bsum,
                                               int* __restrict__ bsumS) {
  __shared__ int s[512];
  const int t = threadIdx.x;
  int v = (t < NB_SCAN) ? bsum[t] : 0;
  s[t] = v;
  __syncthreads();
#pragma unroll
  for (int off = 1; off < 512; off <<= 1) {
    int u = (t >= off) ? s[t - off] : 0;
    __syncthreads();
    s[t] += u;
    __syncthreads();
  }
  if (t < NB_SCAN) bsumS[t] = s[t] - v;
}

__global__ __launch_bounds__(256) void k_scan3(int* __restrict__ start,
                                               int* __restrict__ cursor,
                                               const int* __restrict__ bsumS) {
  int i = blockIdx.x * 256 + threadIdx.x;
  if (i < N_NODES) {
    int val = start[i] + bsumS[blockIdx.x];
    start[i] = val;
    cursor[i] = val;
  }
}

__global__ __launch_bounds__(256) void k_build(const int* __restrict__ row,
                                               const int* __restrict__ col,
                                               const float* __restrict__ dis,
                                               int* __restrict__ cursor,
                                               int2* __restrict__ edata) {
  int e = blockIdx.x * 256 + threadIdx.x;
  if (e >= N_EDGES) return;
  int r = row[e];
  int c = col[e];
  int pos = atomicAdd(&cursor[c], 1);
  edata[pos] = make_int2(r, __float_as_int(dis[r] * dis[c]));
}

// ---------------- GEMM1: h1b = bf16(x @ W1) ----------------

__global__ __launch_bounds__(256) void k_gemm1(const float* __restrict__ x,
                                               const float* __restrict__ W1,
                                               unsigned short* __restrict__ h1b) {
  __shared__ float xs[64 * 68];
  __shared__ float ws[64 * 64];
  const int tid = threadIdx.x;
  const int c0 = (tid & 15) * 4;
  const int r0 = (tid >> 4) * 4;
  const int rowBase = blockIdx.x * 64;

  float acc[4][4];
#pragma unroll
  for (int j = 0; j < 4; ++j)
#pragma unroll
    for (int i = 0; i < 4; ++i) acc[j][i] = 0.0f;

  for (int kc = 0; kc < F_INDIM; kc += 64) {
#pragma unroll
    for (int i = 0; i < 4; ++i) {
      int f = tid + 256 * i;
      int r = f >> 4, kq = f & 15;
      int gr = rowBase + r;
      float4 v = make_float4(0.f, 0.f, 0.f, 0.f);
      if (gr < N_NODES) v = *(const float4*)&x[(size_t)gr * F_INDIM + kc + kq * 4];
      *(float4*)&xs[r * 68 + kq * 4] = v;
    }
#pragma unroll
    for (int i = 0; i < 4; ++i) {
      int f = tid + 256 * i;
      int k = f >> 4, q = f & 15;
      *(float4*)&ws[k * 64 + q * 4] = *(const float4*)&W1[(size_t)(kc + k) * 64 + q * 4];
    }
    __syncthreads();

    for (int k0 = 0; k0 < 64; k0 += 4) {
      float4 xv[4];
#pragma unroll
      for (int j = 0; j < 4; ++j) xv[j] = *(const float4*)&xs[(r0 + j) * 68 + k0];
#pragma unroll
      for (int kk = 0; kk < 4; ++kk) {
        const float4 wv = *(const float4*)&ws[(k0 + kk) * 64 + c0];
#pragma unroll
        for (int j = 0; j < 4; ++j) {
          const float xk = ((const float*)&xv[j])[kk];
          acc[j][0] += xk * wv.x;
          acc[j][1] += xk * wv.y;
          acc[j][2] += xk * wv.z;
          acc[j][3] += xk * wv.w;
        }
      }
    }
    __syncthreads();
  }

#pragma unroll
  for (int j = 0; j < 4; ++j) {
    int gr = rowBase + r0 + j;
    if (gr < N_NODES) {
      ushort4 o;
      o.x = f2bf(acc[j][0]);
      o.y = f2bf(acc[j][1]);
      o.z = f2bf(acc[j][2]);
      o.w = f2bf(acc[j][3]);
      *(ushort4*)&h1b[(size_t)gr * HID + c0] = o;
    }
  }
}

// ---------------- agg1: out1 = dis^2*h1 + sum norm*h1[src]  (bf16 gathers, x4 unroll) ----

__global__ __launch_bounds__(256) void k_agg1(const int2* __restrict__ edata,
                                              const int* __restrict__ start,
                                              const float* __restrict__ dis,
                                              const unsigned short* __restrict__ h1b,
                                              float* __restrict__ out1) {
  int gid = blockIdx.x * 256 + threadIdx.x;
  int wid = gid >> 6;
  int lane = gid & 63;
  if (wid >= N_NODES) return;
  int s0 = start[wid];
  int e0 = start[wid + 1];
  float d = dis[wid];
  float acc = d * d * bf2f(h1b[(size_t)wid * HID + lane]);
  int i = s0;
  for (; i + 4 <= e0; i += 4) {
    int2 ea = edata[i];
    int2 eb = edata[i + 1];
    int2 ec = edata[i + 2];
    int2 ed = edata[i + 3];
    float va = bf2f(h1b[(size_t)ea.x * HID + lane]);
    float vb = bf2f(h1b[(size_t)eb.x * HID + lane]);
    float vc = bf2f(h1b[(size_t)ec.x * HID + lane]);
    float vd = bf2f(h1b[(size_t)ed.x * HID + lane]);
    acc += __int_as_float(ea.y) * va;
    acc += __int_as_float(eb.y) * vb;
    acc += __int_as_float(ec.y) * vc;
    acc += __int_as_float(ed.y) * vd;
  }
  for (; i < e0; ++i) {
    int2 ea = edata[i];
    acc += __int_as_float(ea.y) * bf2f(h1b[(size_t)ea.x * HID + lane]);
  }
  out1[(size_t)wid * HID + lane] = acc;
}

// ---------------- GEMM2: gb = bf16(relu(out1 + b1) @ W2) ----------------

__global__ __launch_bounds__(256) void k_gemm2(const float* __restrict__ out1,
                                               const float* __restrict__ W2,
                                               const float* __restrict__ b1,
                                               unsigned short* __restrict__ gb) {
  __shared__ float xs[128 * 68];
  __shared__ float ws2[64 * NCLS];
  const int tid = threadIdx.x;
  const int c0 = (tid & 7) * 5;
  const int r0 = (tid >> 3) * 4;
  const int rowBase = blockIdx.x * 128;

#pragma unroll
  for (int i = 0; i < 3; ++i) {
    int f = tid + 256 * i;
    if (f < 640) *(float4*)&ws2[f * 4] = *(const float4*)&W2[f * 4];
  }
#pragma unroll
  for (int i = 0; i < 8; ++i) {
    int f = tid + 256 * i;
    int r = f >> 4, kq = f & 15;
    int gr = rowBase + r;
    float4 v = make_float4(0.f, 0.f, 0.f, 0.f);
    if (gr < N_NODES) {
      v = *(const float4*)&out1[(size_t)gr * HID + kq * 4];
      float4 bv = *(const float4*)&b1[kq * 4];
      v.x = fmaxf(v.x + bv.x, 0.f);
      v.y = fmaxf(v.y + bv.y, 0.f);
      v.z = fmaxf(v.z + bv.z, 0.f);
      v.w = fmaxf(v.w + bv.w, 0.f);
    }
    *(float4*)&xs[r * 68 + kq * 4] = v;
  }
  __syncthreads();

  float acc[4][5];
#pragma unroll
  for (int j = 0; j < 4; ++j)
#pragma unroll
    for (int i = 0; i < 5; ++i) acc[j][i] = 0.0f;

  for (int k0 = 0; k0 < HID; k0 += 4) {
    float4 xv[4];
#pragma unroll
    for (int j = 0; j < 4; ++j) xv[j] = *(const float4*)&xs[(r0 + j) * 68 + k0];
#pragma unroll
    for (int kk = 0; kk < 4; ++kk) {
      const float* wrow = &ws2[(k0 + kk) * NCLS + c0];
      float w0 = wrow[0], w1 = wrow[1], w2 = wrow[2], w3 = wrow[3], w4 = wrow[4];
#pragma unroll
      for (int j = 0; j < 4; ++j) {
        const float xk = ((const float*)&xv[j])[kk];
        acc[j][0] += xk * w0;
        acc[j][1] += xk * w1;
        acc[j][2] += xk * w2;
        acc[j][3] += xk * w3;
        acc[j][4] += xk * w4;
      }
    }
  }

#pragma unroll
  for (int j = 0; j < 4; ++j) {
    int gr = rowBase + r0 + j;
    if (gr < N_NODES) {
#pragma unroll
      for (int i = 0; i < 5; ++i)
        gb[(size_t)gr * NCLS + c0 + i] = f2bf(acc[j][i]);
    }
  }
}

// ---------------- agg2: out = dis^2*g + sum norm*g[src]  (bf16 gathers, x4 unroll) ------

__global__ __launch_bounds__(256) void k_agg2(const int2* __restrict__ edata,
                                              const int* __restrict__ start,
                                              const float* __restrict__ dis,
                                              const unsigned short* __restrict__ gb,
                                              float* __restrict__ out) {
  int gid = blockIdx.x * 256 + threadIdx.x;
  if (gid >= N_NODES * NCLS) return;
  int node = gid / NCLS;
  int f = gid - node * NCLS;
  int s0 = start[node];
  int e0 = start[node + 1];
  float d = dis[node];
  float acc = d * d * bf2f(gb[(size_t)node * NCLS + f]);
  int i = s0;
  for (; i + 4 <= e0; i += 4) {
    int2 ea = edata[i];
    int2 eb = edata[i + 1];
    int2 ec = edata[i + 2];
    int2 ed = edata[i + 3];
    float va = bf2f(gb[(size_t)ea.x * NCLS + f]);
    float vb = bf2f(gb[(size_t)eb.x * NCLS + f]);
    float vc = bf2f(gb[(size_t)ec.x * NCLS + f]);
    float vd = bf2f(gb[(size_t)ed.x * NCLS + f]);
    acc += __int_as_float(ea.y) * va;
    acc += __int_as_float(eb.y) * vb;
    acc += __int_as_float(ec.y) * vc;
    acc += __int_as_float(ed.y) * vd;
  }
  for (; i < e0; ++i) {
    int2 ea = edata[i];
    acc += __int_as_float(ea.y) * bf2f(gb[(size_t)ea.x * NCLS + f]);
  }
  out[(size_t)node * NCLS + f] = acc;
}

// ---------------- log_softmax (adds b2), one wave per row ----------------

__global__ __launch_bounds__(256) void k_logsoftmax(float* __restrict__ out,
                                                    const float* __restrict__ b2) {
  int gid = blockIdx.x * 256 + threadIdx.x;
  int wid = gid >> 6;
  int lane = threadIdx.x & 63;
  if (wid >= N_NODES) return;
  float val = 0.0f;
  float v = -INFINITY;
  if (lane < NCLS) {
    val = out[(size_t)wid * NCLS + lane] + b2[lane];
    v = val;
  }
#pragma unroll
  for (int off = 32; off > 0; off >>= 1) v = fmaxf(v, __shfl_xor(v, off));
  float ex = (lane < NCLS) ? expf(val - v) : 0.0f;
  float s = ex;
#pragma unroll
  for (int off = 32; off > 0; off >>= 1) s += __shfl_xor(s, off);
  float ls = logf(s);
  if (lane < NCLS) out[(size_t)wid * NCLS + lane] = val - v - ls;
}

// ---------------- launch ----------------

extern "C" void kernel_launch(void* const* d_in, const int* in_sizes, int n_in,
                              void* d_out, int out_size, void* d_ws, size_t ws_size,
                              hipStream_t stream) {
  const float* x  = (const float*)d_in[0];
  const int*   ei = (const int*)d_in[1];
  const float* W1 = (const float*)d_in[2];
  const float* b1 = (const float*)d_in[3];
  const float* W2 = (const float*)d_in[4];
  const float* b2 = (const float*)d_in[5];
  float* out = (float*)d_out;

  const int* row = ei;             // edge_index[0] = src
  const int* col = ei + N_EDGES;   // edge_index[1] = dst

  // workspace layout
  int2*           edata  = (int2*)d_ws;                          // E       (12.8 MB)
  unsigned short* h1b    = (unsigned short*)(edata + N_EDGES);   // N*64 bf16 (12.8 MB)
  float*          out1   = (float*)(h1b + (size_t)N_NODES * HID);// N*64 fp32 (25.6 MB)
  float*          dis    = out1 + (size_t)N_NODES * HID;         // N
  int*            degi   = (int*)(dis + N_NODES);                // N
  int*            start  = degi + N_NODES;                       // N+1
  int*            cursor = start + N_NODES + 1;                  // N
  int*            bsum   = cursor + N_NODES;                     // NB_SCAN
  int*            bsumS  = bsum + NB_SCAN;                       // NB_SCAN
  unsigned short* gb     = h1b;                                  // N*40 bf16, reuse

  const int gridN = (N_NODES + 255) / 256;     // 391
  const int gridE = (N_EDGES + 255) / 256;

  k_zero_deg<<<gridN, 256, 0, stream>>>(degi);
  k_count<<<gridE, 256, 0, stream>>>(col, degi);
  k_dis<<<gridN, 256, 0, stream>>>(degi, dis, start);
  k_scan1<<<gridN, 256, 0, stream>>>(degi, start, bsum);
  k_scan2<<<1, 512, 0, stream>>>(bsum, bsumS);
  k_scan3<<<gridN, 256, 0, stream>>>(start, cursor, bsumS);
  k_build<<<gridE, 256, 0, stream>>>(row, col, dis, cursor, edata);

  k_gemm1<<<(N_NODES + 63) / 64, 256, 0, stream>>>(x, W1, h1b);
  k_agg1<<<(N_NODES * 64 + 255) / 256, 256, 0, stream>>>(edata, start, dis, h1b, out1);

  k_gemm2<<<(N_NODES + 127) / 128, 256, 0, stream>>>(out1, W2, b1, gb);
  k_agg2<<<(N_NODES * NCLS + 255) / 256, 256, 0, stream>>>(edata, start, dis, gb, out);

  k_logsoftmax<<<(N_NODES * 64 + 255) / 256, 256, 0, stream>>>(out, b2);
}